// Round 1
// baseline (287.344 us; speedup 1.0000x reference)
//
#include <hip/hip_runtime.h>

typedef _Float16 half8 __attribute__((ext_vector_type(8)));
typedef float    floatx16 __attribute__((ext_vector_type(16)));
typedef float    float4v __attribute__((ext_vector_type(4)));

#define K_DIM 256
#define N_DIM 256
#define BM 64
#define BK 64

// Build W^T in f16 bit patterns: W[k][n] = 2^shift[k][n] * (-1)^sign[k][n]
// shift is an exact integer in [-10,-1]; 2^shift is exact in f16 (exp field 5..14).
__global__ __launch_bounds__(256) void build_wT(const float* __restrict__ shift,
                                                const float* __restrict__ sgn,
                                                unsigned short* __restrict__ wT) {
    int idx = blockIdx.x * 256 + threadIdx.x;   // idx = k*256 + n
    int k = idx >> 8, n = idx & 255;
    float sh = shift[idx];
    float sg = sgn[idx];
    int e = 15 + (int)sh;                       // f16 exponent field, 5..14
    unsigned short wv = (unsigned short)(((sg != 0.0f) ? 0x8000 : 0) | (e << 10));
    wT[n * 256 + k] = wv;                       // W^T[n][k], row = 256 f16 (contiguous K)
}

__global__ __launch_bounds__(256) void dense_shift_gemm(
        const float* __restrict__ x,
        const unsigned short* __restrict__ wT,
        const float* __restrict__ bias,
        float* __restrict__ out) {
    // A tile, f16, double-buffered, XOR-swizzled (rows are 128 B -> would be
    // same-bank on ds_read_b128 without the swizzle; byte ^= (row&7)<<4).
    __shared__ __align__(16) unsigned short aLds[2][BM * BK];   // 2 x 8 KB

    const int t = threadIdx.x;
    const int w = t >> 6;            // wave 0..3  -> owns cols [w*64, w*64+64)
    const int l = t & 63;
    const long m0 = (long)blockIdx.x * BM;

    // ---- staging: thread t loads 8 consecutive floats of row sr (and sr+32) ----
    const int sr  = t >> 3;                  // 0..31
    const int scf = (t & 7) * 8;             // col (floats / f16 units), 0..56
    const float* xp0 = x + (m0 + sr) * K_DIM + scf;
    const float* xp1 = xp0 + 32 * (long)K_DIM;
    const int swzS  = (sr & 7) << 3;         // swizzle in ushort units
    const int w0idx = sr        * BK + (scf ^ swzS);
    const int w1idx = (sr + 32) * BK + (scf ^ swzS);   // (sr+32)&7 == sr&7

    float4v L00, L01, L10, L11;

#define ISSUE(kc) do {                                        \
        const float* p0_ = xp0 + (kc) * BK;                   \
        const float* p1_ = xp1 + (kc) * BK;                   \
        L00 = *(const float4v*)p0_;                           \
        L01 = *(const float4v*)(p0_ + 4);                     \
        L10 = *(const float4v*)p1_;                           \
        L11 = *(const float4v*)(p1_ + 4);                     \
    } while (0)

#define WRITE(buf) do {                                       \
        half8 h0_, h1_;                                       \
        h0_[0]=(_Float16)L00[0]; h0_[1]=(_Float16)L00[1];     \
        h0_[2]=(_Float16)L00[2]; h0_[3]=(_Float16)L00[3];     \
        h0_[4]=(_Float16)L01[0]; h0_[5]=(_Float16)L01[1];     \
        h0_[6]=(_Float16)L01[2]; h0_[7]=(_Float16)L01[3];     \
        h1_[0]=(_Float16)L10[0]; h1_[1]=(_Float16)L10[1];     \
        h1_[2]=(_Float16)L10[2]; h1_[3]=(_Float16)L10[3];     \
        h1_[4]=(_Float16)L11[0]; h1_[5]=(_Float16)L11[1];     \
        h1_[6]=(_Float16)L11[2]; h1_[7]=(_Float16)L11[3];     \
        *reinterpret_cast<half8*>(&aLds[buf][w0idx]) = h0_;   \
        *reinterpret_cast<half8*>(&aLds[buf][w1idx]) = h1_;   \
    } while (0)

    // ---- fragment addressing ----
    const int ln31 = l & 31;
    const int lh   = l >> 5;                  // k-half (0/1)
    const int sx   = (ln31 & 7) << 3;         // read-side swizzle XOR (ushort units)
    const int arow0 = ln31 * BK;              // mb = 0
    const int arow1 = (32 + ln31) * BK;       // mb = 1
    const unsigned short* bp0 = wT + (long)(w * 64 + ln31) * K_DIM + lh * 8;  // nb = 0
    const unsigned short* bp1 = bp0 + 32 * (long)K_DIM;                        // nb = 1

    floatx16 acc00 = {0,0,0,0,0,0,0,0,0,0,0,0,0,0,0,0};
    floatx16 acc01 = {0,0,0,0,0,0,0,0,0,0,0,0,0,0,0,0};
    floatx16 acc10 = {0,0,0,0,0,0,0,0,0,0,0,0,0,0,0,0};
    floatx16 acc11 = {0,0,0,0,0,0,0,0,0,0,0,0,0,0,0,0};

#define COMPUTE(kc, buf) do {                                                    \
        _Pragma("unroll")                                                        \
        for (int ks = 0; ks < 4; ++ks) {                                         \
            const int ac_ = (ks * 16 + lh * 8) ^ sx;                             \
            half8 a0_ = *reinterpret_cast<const half8*>(&aLds[buf][arow0 + ac_]);\
            half8 a1_ = *reinterpret_cast<const half8*>(&aLds[buf][arow1 + ac_]);\
            half8 b0_ = *reinterpret_cast<const half8*>(bp0 + (kc) * BK + ks * 16);\
            half8 b1_ = *reinterpret_cast<const half8*>(bp1 + (kc) * BK + ks * 16);\
            acc00 = __builtin_amdgcn_mfma_f32_32x32x16_f16(a0_, b0_, acc00, 0, 0, 0);\
            acc01 = __builtin_amdgcn_mfma_f32_32x32x16_f16(a0_, b1_, acc01, 0, 0, 0);\
            acc10 = __builtin_amdgcn_mfma_f32_32x32x16_f16(a1_, b0_, acc10, 0, 0, 0);\
            acc11 = __builtin_amdgcn_mfma_f32_32x32x16_f16(a1_, b1_, acc11, 0, 0, 0);\
        }                                                                        \
    } while (0)

    // ---- pipeline: 4 K-chunks, double-buffered LDS, loads issued one chunk ahead ----
    ISSUE(0);
    WRITE(0);
    ISSUE(1);
    __syncthreads();

    COMPUTE(0, 0);
    WRITE(1); ISSUE(2); __syncthreads();
    COMPUTE(1, 1);
    WRITE(0); ISSUE(3); __syncthreads();
    COMPUTE(2, 0);
    WRITE(1); __syncthreads();
    COMPUTE(3, 1);

    // ---- epilogue: bias + store (C layout: col=lane&31, row=(r&3)+8*(r>>2)+4*(lane>>5)) ----
    const long col0 = w * 64 + ln31;
    const float bv0 = bias[col0];
    const float bv1 = bias[col0 + 32];
    const int rbase = 4 * lh;

#pragma unroll
    for (int r = 0; r < 16; ++r) {
        const long row = (r & 3) + 8 * (r >> 2) + rbase;
        out[(m0 + row) * N_DIM + col0]           = acc00[r] + bv0;
        out[(m0 + row) * N_DIM + col0 + 32]      = acc01[r] + bv1;
        out[(m0 + 32 + row) * N_DIM + col0]      = acc10[r] + bv0;
        out[(m0 + 32 + row) * N_DIM + col0 + 32] = acc11[r] + bv1;
    }

#undef ISSUE
#undef WRITE
#undef COMPUTE
}

extern "C" void kernel_launch(void* const* d_in, const int* in_sizes, int n_in,
                              void* d_out, int out_size, void* d_ws, size_t ws_size,
                              hipStream_t stream) {
    const float* x     = (const float*)d_in[0];
    const float* shift = (const float*)d_in[1];
    const float* sgn   = (const float*)d_in[2];
    const float* bias  = (const float*)d_in[3];
    float* out = (float*)d_out;
    unsigned short* wT = (unsigned short*)d_ws;   // 256*256*2 = 128 KB scratch

    build_wT<<<256, 256, 0, stream>>>(shift, sgn, wT);

    const int nblocks = 524288 / BM;   // 8192
    dense_shift_gemm<<<nblocks, 256, 0, stream>>>(x, wT, bias, out);
}